// Round 2
// baseline (304.249 us; speedup 1.0000x reference)
//
#include <hip/hip_runtime.h>
#include <hip/hip_bf16.h>

// SphereConv N=2, CIN=64, COUT=64, H=256, W=512, K2=9.
// Round 5 == Round 4 resubmit (round 4 bench died to a container-acquire
// infra failure; bounds/alignment audit found no crash vector in the code).
// Barrier-free restructure: each lane gathers+interps the 8 channels x 4
// corners of its OWN MFMA B-fragment element (B-frag lane l holds
// k=(l>>4)*8+j, col=l&15), so the interpolated result packs directly into
// the MFMA B operand. No LDS staging, no __syncthreads in the main loop,
// waves fully independent. Per-tap bilinear params computed per-lane from
// pos (f32 weights, no bf16 roundtrip). wTr / xt layouts unchanged.

constexpr int N_ = 2;
constexpr int CIN = 64;
constexpr int COUT = 64;
constexpr int H_ = 256;
constexpr int W_ = 512;
constexpr int K2 = 9;
constexpr int HW = H_ * W_;
constexpr int NSTEP = (CIN * K2) / 32;  // 18
constexpr int PTILE = 128;

typedef __attribute__((ext_vector_type(8))) short short8;
typedef __attribute__((ext_vector_type(4))) float floatx4;
typedef __attribute__((ext_vector_type(2))) float floatx2;

__device__ __forceinline__ float bfhi2f(unsigned u) {  // already-positioned bits
  return __uint_as_float(u);
}

// wTr[(ot*18 + s)*64*8 + lane*8 + j] = bf16(weight[o = 16*ot + (lane&15)]
//                                           [kk = 32s + (lane>>4)*8 + j])
__global__ void prep_w(const float* __restrict__ w, ushort* __restrict__ wTr) {
  int i = blockIdx.x * blockDim.x + threadIdx.x;
  if (i >= 4 * NSTEP * 64 * 8) return;
  int j = i & 7;
  int lane = (i >> 3) & 63;
  int s = (i >> 9) % NSTEP;
  int ot = i / (512 * NSTEP);
  int o = ot * 16 + (lane & 15);
  int kk = s * 32 + (lane >> 4) * 8 + j;
  int tap = kk >> 6, c = kk & 63;
  __hip_bfloat16 b = __float2bfloat16(w[(o * CIN + c) * K2 + tap]);
  wTr[i] = *(ushort*)&b;
}

// x[n][c][hw] fp32 -> xt[n][hw][c] bf16, via LDS tile (64 px x 64 ch).
// float4 loads (4x fewer load instructions than round 3).
__global__ __launch_bounds__(256) void transpose_x(
    const float* __restrict__ x, ushort* __restrict__ xt) {
  __shared__ ushort tile[64 * 72];
  int b = blockIdx.x;
  int n = b >> 11;
  int hw0 = (b & 2047) * 64;
  int tid = threadIdx.x;
  int px4 = (tid & 15) * 4;
  int cq = tid >> 4;  // 0..15
  const float* xn = x + (size_t)n * CIN * HW;
#pragma unroll
  for (int it = 0; it < 4; ++it) {
    int c = it * 16 + cq;
    float4 v = *(const float4*)&xn[(size_t)c * HW + hw0 + px4];
    __hip_bfloat16 b0 = __float2bfloat16(v.x);
    __hip_bfloat16 b1 = __float2bfloat16(v.y);
    __hip_bfloat16 b2 = __float2bfloat16(v.z);
    __hip_bfloat16 b3 = __float2bfloat16(v.w);
    tile[(px4 + 0) * 72 + c] = *(ushort*)&b0;
    tile[(px4 + 1) * 72 + c] = *(ushort*)&b1;
    tile[(px4 + 2) * 72 + c] = *(ushort*)&b2;
    tile[(px4 + 3) * 72 + c] = *(ushort*)&b3;
  }
  __syncthreads();
  ushort* xtn = xt + (size_t)n * HW * CIN;
#pragma unroll
  for (int it = 0; it < 2; ++it) {
    int task = it * 256 + tid;
    int px2 = task >> 3, chunk = task & 7;
    uint4 v = *(uint4*)&tile[px2 * 72 + chunk * 8];
    *(uint4*)&xtn[(size_t)(hw0 + px2) * 64 + chunk * 8] = v;
  }
}

__global__ __launch_bounds__(256, 4) void sphere_conv_mfma(
    const ushort* __restrict__ xt, const ushort* __restrict__ wTr,
    const float* __restrict__ pos, float* __restrict__ out) {
  int tid = threadIdx.x;
  int blk = blockIdx.x;
  int n = blk >> 10;
  int ptile = (blk & 1023) * PTILE;
  int lane = tid & 63, wv = tid >> 6;
  int col = lane & 15, quad = lane >> 4;

  // This wave owns 32 pixels (2 MFMA n-tiles) x all 64 COUT (4 A-tiles).
  int hw[2];
  hw[0] = ptile + wv * 32 + col;
  hw[1] = hw[0] + 16;

  const ushort* xtn = xt + (size_t)n * HW * CIN;

  floatx4 acc[2][4];
#pragma unroll
  for (int T = 0; T < 2; ++T)
#pragma unroll
    for (int ot = 0; ot < 4; ++ot) acc[T][ot] = (floatx4)0.f;

  int o00[2], dxo[2], dyo[2];  // ushort-unit offsets into xtn
  float w4[2][4];

#pragma unroll
  for (int s = 0; s < NSTEP; ++s) {
    if ((s & 1) == 0) {  // tap changes every 2 steps; params per-lane
      int t = s >> 1;
#pragma unroll
      for (int T = 0; T < 2; ++T) {
        float py = pos[(2 * t + 0) * HW + hw[T]];
        float pxx = pos[(2 * t + 1) * HW + hw[T]];
        float y0f = floorf(py), x0f = floorf(pxx);
        float dy = py - y0f, dx = pxx - x0f;
        float y1f = y0f + 1.f, x1f = x0f + 1.f;
        float vy0 = (y0f >= 0.f && y0f <= (float)(H_ - 1)) ? 1.f : 0.f;
        float vy1 = (y1f >= 0.f && y1f <= (float)(H_ - 1)) ? 1.f : 0.f;
        float vx0 = (x0f >= 0.f && x0f <= (float)(W_ - 1)) ? 1.f : 0.f;
        float vx1 = (x1f >= 0.f && x1f <= (float)(W_ - 1)) ? 1.f : 0.f;
        w4[T][0] = (1.f - dy) * (1.f - dx) * vy0 * vx0;
        w4[T][1] = (1.f - dy) * dx * vy0 * vx1;
        w4[T][2] = dy * (1.f - dx) * vy1 * vx0;
        w4[T][3] = dy * dx * vy1 * vx1;
        int y0c = (int)fminf(fmaxf(y0f, 0.f), (float)(H_ - 1));
        int y1c = (int)fminf(fmaxf(y1f, 0.f), (float)(H_ - 1));
        int x0c = (int)fminf(fmaxf(x0f, 0.f), (float)(W_ - 1));
        int x1c = (int)fminf(fmaxf(x1f, 0.f), (float)(W_ - 1));
        o00[T] = (y0c * W_ + x0c) * CIN;
        dxo[T] = (x1c - x0c) * CIN;
        dyo[T] = (y1c - y0c) * (W_ * CIN);
      }
    }
    // B-frag element j of this lane = channel c0 + j of pixel hw[T].
    int c0 = ((s & 1) << 5) + (quad << 3);

    short8 g[2][4];
#pragma unroll
    for (int T = 0; T < 2; ++T) {
      const ushort* p00 = xtn + (size_t)o00[T] + c0;
      const ushort* p10 = p00 + dyo[T];
      g[T][0] = *(const short8*)p00;
      g[T][1] = *(const short8*)(p00 + dxo[T]);
      g[T][2] = *(const short8*)p10;
      g[T][3] = *(const short8*)(p10 + dxo[T]);
    }

    short8 afr[4];
#pragma unroll
    for (int ot = 0; ot < 4; ++ot)
      afr[ot] = *(const short8*)(wTr + ((size_t)(ot * NSTEP + s) * 64 + lane) * 8);

    short8 bfr[2];
#pragma unroll
    for (int T = 0; T < 2; ++T) {
      const unsigned* u = (const unsigned*)&g[T][0];
      floatx2 a2[4];
#pragma unroll
      for (int d = 0; d < 4; ++d) {
        floatx2 f = {bfhi2f(u[d] << 16), bfhi2f(u[d] & 0xFFFF0000u)};
        a2[d] = floatx2{w4[T][0], w4[T][0]} * f;
      }
#pragma unroll
      for (int c = 1; c < 4; ++c) {
#pragma unroll
        for (int d = 0; d < 4; ++d) {
          unsigned v = u[c * 4 + d];
          floatx2 f = {bfhi2f(v << 16), bfhi2f(v & 0xFFFF0000u)};
          a2[d] = __builtin_elementwise_fma(floatx2{w4[T][c], w4[T][c]}, f, a2[d]);
        }
      }
      union { unsigned q[4]; short8 s8; } pk;
#pragma unroll
      for (int d = 0; d < 4; ++d) {
        __hip_bfloat16 lo = __float2bfloat16(a2[d].x);
        __hip_bfloat16 hi = __float2bfloat16(a2[d].y);
        pk.q[d] = ((unsigned)*(ushort*)&hi << 16) | *(ushort*)&lo;
      }
      bfr[T] = pk.s8;
    }

#pragma unroll
    for (int T = 0; T < 2; ++T)
#pragma unroll
      for (int ot = 0; ot < 4; ++ot)
        acc[T][ot] = __builtin_amdgcn_mfma_f32_16x16x32_bf16(afr[ot], bfr[T], acc[T][ot], 0, 0, 0);
  }

  // ---- epilogue: D row = quad*4+r (COUT within A-tile), col = pixel ----
#pragma unroll
  for (int T = 0; T < 2; ++T)
#pragma unroll
    for (int ot = 0; ot < 4; ++ot)
#pragma unroll
      for (int r = 0; r < 4; ++r) {
        int o = ot * 16 + quad * 4 + r;
        out[(size_t)(n * COUT + o) * HW + ptile + wv * 32 + T * 16 + col] =
            acc[T][ot][r];
      }
}

extern "C" void kernel_launch(void* const* d_in, const int* in_sizes, int n_in,
                              void* d_out, int out_size, void* d_ws, size_t ws_size,
                              hipStream_t stream) {
  const float* x   = (const float*)d_in[0];  // (2, 64, 256, 512) fp32
  const float* w   = (const float*)d_in[1];  // (64, 64, 3, 3) fp32
  const float* pos = (const float*)d_in[2];  // (18, 256, 512) fp32
  float* out = (float*)d_out;                // (2, 64, 256, 512) fp32

  // ws layout: wTr bf16 [72 KB] at 0; xt bf16 [33.6 MB] at 128 KB.
  ushort* wTr = (ushort*)d_ws;
  ushort* xt = (ushort*)((char*)d_ws + (128 << 10));

  prep_w<<<(4 * NSTEP * 64 * 8 + 255) / 256, 256, 0, stream>>>(w, wTr);
  transpose_x<<<N_ * (HW / 64), 256, 0, stream>>>(x, xt);

  int nblk = N_ * (HW / PTILE);  // 2048
  sphere_conv_mfma<<<nblk, 256, 0, stream>>>(xt, wTr, pos, out);
}

// Round 3
// 283.543 us; speedup vs baseline: 1.0730x; 1.0730x over previous
//
#include <hip/hip_runtime.h>
#include <hip/hip_bf16.h>

// SphereConv N=2, CIN=64, COUT=64, H=256, W=512, K2=9.
// Round 6: round-5 barrier-free MFMA-direct structure +
//  (1) XCD-chunked block swizzle: blk=(orig&7)*256+(orig>>3). Restores
//      cross-tap L2 reuse (round-5 FETCH was 303 MB = 2n x 9 taps x 16.8 MB
//      = whole-image refetch per tap; tiles sharing tap rows were landing
//      on different XCD L2s under round-robin dispatch).
//  (2) explicit next-step gather prefetch (ping-pong params per tap parity,
//      all indices compile-time under full unroll); launch_bounds(256,3)
//      so the prefetch registers (~150 VGPR) don't spill.
//  (3) epilogue via per-wave LDS bounce -> float4 full-line stores
//      (round-5 WRITE_SIZE was 174 MB vs 67 MB of output).

constexpr int N_ = 2;
constexpr int CIN = 64;
constexpr int COUT = 64;
constexpr int H_ = 256;
constexpr int W_ = 512;
constexpr int K2 = 9;
constexpr int HW = H_ * W_;
constexpr int NSTEP = (CIN * K2) / 32;  // 18
constexpr int PTILE = 128;
constexpr int OROW = 36;  // epilogue LDS row stride (floats); 144 B, 16B-aligned

typedef __attribute__((ext_vector_type(8))) short short8;
typedef __attribute__((ext_vector_type(4))) float floatx4;
typedef __attribute__((ext_vector_type(2))) float floatx2;

__device__ __forceinline__ float bfhi2f(unsigned u) {  // already-positioned bits
  return __uint_as_float(u);
}

// wTr[(ot*18 + s)*64*8 + lane*8 + j] = bf16(weight[o = 16*ot + (lane&15)]
//                                           [kk = 32s + (lane>>4)*8 + j])
__global__ void prep_w(const float* __restrict__ w, ushort* __restrict__ wTr) {
  int i = blockIdx.x * blockDim.x + threadIdx.x;
  if (i >= 4 * NSTEP * 64 * 8) return;
  int j = i & 7;
  int lane = (i >> 3) & 63;
  int s = (i >> 9) % NSTEP;
  int ot = i / (512 * NSTEP);
  int o = ot * 16 + (lane & 15);
  int kk = s * 32 + (lane >> 4) * 8 + j;
  int tap = kk >> 6, c = kk & 63;
  __hip_bfloat16 b = __float2bfloat16(w[(o * CIN + c) * K2 + tap]);
  wTr[i] = *(ushort*)&b;
}

// x[n][c][hw] fp32 -> xt[n][hw][c] bf16, via LDS tile (64 px x 64 ch).
__global__ __launch_bounds__(256) void transpose_x(
    const float* __restrict__ x, ushort* __restrict__ xt) {
  __shared__ ushort tile[64 * 72];
  int b = blockIdx.x;
  int n = b >> 11;
  int hw0 = (b & 2047) * 64;
  int tid = threadIdx.x;
  int px4 = (tid & 15) * 4;
  int cq = tid >> 4;  // 0..15
  const float* xn = x + (size_t)n * CIN * HW;
#pragma unroll
  for (int it = 0; it < 4; ++it) {
    int c = it * 16 + cq;
    float4 v = *(const float4*)&xn[(size_t)c * HW + hw0 + px4];
    __hip_bfloat16 b0 = __float2bfloat16(v.x);
    __hip_bfloat16 b1 = __float2bfloat16(v.y);
    __hip_bfloat16 b2 = __float2bfloat16(v.z);
    __hip_bfloat16 b3 = __float2bfloat16(v.w);
    tile[(px4 + 0) * 72 + c] = *(ushort*)&b0;
    tile[(px4 + 1) * 72 + c] = *(ushort*)&b1;
    tile[(px4 + 2) * 72 + c] = *(ushort*)&b2;
    tile[(px4 + 3) * 72 + c] = *(ushort*)&b3;
  }
  __syncthreads();
  ushort* xtn = xt + (size_t)n * HW * CIN;
#pragma unroll
  for (int it = 0; it < 2; ++it) {
    int task = it * 256 + tid;
    int px2 = task >> 3, chunk = task & 7;
    uint4 v = *(uint4*)&tile[px2 * 72 + chunk * 8];
    *(uint4*)&xtn[(size_t)(hw0 + px2) * 64 + chunk * 8] = v;
  }
}

__global__ __launch_bounds__(256, 3) void sphere_conv_mfma(
    const ushort* __restrict__ xt, const ushort* __restrict__ wTr,
    const float* __restrict__ pos, float* __restrict__ out) {
  __shared__ float lds_o[4][64 * OROW];  // 36.9 KB, per-wave epilogue bounce

  int tid = threadIdx.x;
  // XCD-chunked swizzle: consecutive tiles share an XCD's L2 (8 chunks x 256).
  int orig = blockIdx.x;
  int blk = (orig & 7) * 256 + (orig >> 3);
  int n = blk >> 10;
  int ptile = (blk & 1023) * PTILE;
  int lane = tid & 63, wv = tid >> 6;
  int col = lane & 15, quad = lane >> 4;

  // This wave owns 32 pixels (2 MFMA n-tiles) x all 64 COUT (4 A-tiles).
  int hw[2];
  hw[0] = ptile + wv * 32 + col;
  hw[1] = hw[0] + 16;

  const ushort* xtn = xt + (size_t)n * HW * CIN;

  floatx4 acc[2][4];
#pragma unroll
  for (int T = 0; T < 2; ++T)
#pragma unroll
    for (int ot = 0; ot < 4; ++ot) acc[T][ot] = (floatx4)0.f;

  // bilinear params, ping-pong by tap parity (all indices compile-time)
  int o00[2][2], dxo[2][2], dyo[2][2];
  float w4[2][2][4];

  auto calcParams = [&](int t) {
    int tp = t & 1;
#pragma unroll
    for (int T = 0; T < 2; ++T) {
      float py = pos[(2 * t + 0) * HW + hw[T]];
      float pxx = pos[(2 * t + 1) * HW + hw[T]];
      float y0f = floorf(py), x0f = floorf(pxx);
      float dy = py - y0f, dx = pxx - x0f;
      float y1f = y0f + 1.f, x1f = x0f + 1.f;
      float vy0 = (y0f >= 0.f && y0f <= (float)(H_ - 1)) ? 1.f : 0.f;
      float vy1 = (y1f >= 0.f && y1f <= (float)(H_ - 1)) ? 1.f : 0.f;
      float vx0 = (x0f >= 0.f && x0f <= (float)(W_ - 1)) ? 1.f : 0.f;
      float vx1 = (x1f >= 0.f && x1f <= (float)(W_ - 1)) ? 1.f : 0.f;
      w4[tp][T][0] = (1.f - dy) * (1.f - dx) * vy0 * vx0;
      w4[tp][T][1] = (1.f - dy) * dx * vy0 * vx1;
      w4[tp][T][2] = dy * (1.f - dx) * vy1 * vx0;
      w4[tp][T][3] = dy * dx * vy1 * vx1;
      int y0c = (int)fminf(fmaxf(y0f, 0.f), (float)(H_ - 1));
      int y1c = (int)fminf(fmaxf(y1f, 0.f), (float)(H_ - 1));
      int x0c = (int)fminf(fmaxf(x0f, 0.f), (float)(W_ - 1));
      int x1c = (int)fminf(fmaxf(x1f, 0.f), (float)(W_ - 1));
      o00[tp][T] = (y0c * W_ + x0c) * CIN;
      dxo[tp][T] = (x1c - x0c) * CIN;
      dyo[tp][T] = (y1c - y0c) * (W_ * CIN);
    }
  };

  // B-frag element j of lane = channel c0 + j of pixel hw[T].
  auto gather = [&](int s, short8 (&g)[2][4]) {
    int tp = (s >> 1) & 1;
    int c0 = ((s & 1) << 5) + (quad << 3);
#pragma unroll
    for (int T = 0; T < 2; ++T) {
      const ushort* p00 = xtn + (size_t)o00[tp][T] + c0;
      const ushort* p10 = p00 + dyo[tp][T];
      g[T][0] = *(const short8*)p00;
      g[T][1] = *(const short8*)(p00 + dxo[tp][T]);
      g[T][2] = *(const short8*)p10;
      g[T][3] = *(const short8*)(p10 + dxo[tp][T]);
    }
  };

  calcParams(0);
  short8 gA[2][4], gB[2][4];
  gather(0, gA);

#pragma unroll
  for (int s = 0; s < NSTEP; ++s) {
    if (s + 1 < NSTEP) {  // prefetch next step (params first at tap boundary)
      if (((s + 1) & 1) == 0) calcParams((s + 1) >> 1);
      gather(s + 1, gB);
    }

    int tp = (s >> 1) & 1;
    short8 afr[4];
#pragma unroll
    for (int ot = 0; ot < 4; ++ot)
      afr[ot] = *(const short8*)(wTr + ((size_t)(ot * NSTEP + s) * 64 + lane) * 8);

    short8 bfr[2];
#pragma unroll
    for (int T = 0; T < 2; ++T) {
      const unsigned* u = (const unsigned*)&gA[T][0];
      floatx2 a2[4];
#pragma unroll
      for (int d = 0; d < 4; ++d) {
        floatx2 f = {bfhi2f(u[d] << 16), bfhi2f(u[d] & 0xFFFF0000u)};
        a2[d] = floatx2{w4[tp][T][0], w4[tp][T][0]} * f;
      }
#pragma unroll
      for (int c = 1; c < 4; ++c) {
#pragma unroll
        for (int d = 0; d < 4; ++d) {
          unsigned v = u[c * 4 + d];
          floatx2 f = {bfhi2f(v << 16), bfhi2f(v & 0xFFFF0000u)};
          a2[d] = __builtin_elementwise_fma(floatx2{w4[tp][T][c], w4[tp][T][c]}, f, a2[d]);
        }
      }
      union { unsigned q[4]; short8 s8; } pk;
#pragma unroll
      for (int d = 0; d < 4; ++d) {
        __hip_bfloat16 lo = __float2bfloat16(a2[d].x);
        __hip_bfloat16 hi = __float2bfloat16(a2[d].y);
        pk.q[d] = ((unsigned)*(ushort*)&hi << 16) | *(ushort*)&lo;
      }
      bfr[T] = pk.s8;
    }

#pragma unroll
    for (int T = 0; T < 2; ++T)
#pragma unroll
      for (int ot = 0; ot < 4; ++ot)
        acc[T][ot] = __builtin_amdgcn_mfma_f32_16x16x32_bf16(afr[ot], bfr[T], acc[T][ot], 0, 0, 0);

    if (s + 1 < NSTEP) {  // SSA rename under full unroll, no real movs
#pragma unroll
      for (int T = 0; T < 2; ++T)
#pragma unroll
        for (int q = 0; q < 4; ++q) gA[T][q] = gB[T][q];
    }
  }

  // ---- epilogue: per-wave LDS bounce -> full-line float4 stores ----
  // acc[T][ot][r] is out row o=ot*16+quad*4+r, px = wv*32 + T*16 + col.
  float* lo = lds_o[wv];
#pragma unroll
  for (int T = 0; T < 2; ++T)
#pragma unroll
    for (int ot = 0; ot < 4; ++ot)
#pragma unroll
      for (int r = 0; r < 4; ++r)
        lo[(ot * 16 + quad * 4 + r) * OROW + T * 16 + col] = acc[T][ot][r];
  // same-wave write->read: no barrier needed (lgkmcnt handled by compiler)
#pragma unroll
  for (int it = 0; it < 2; ++it) {
    int task = it * 64 + lane;
    int o = task >> 1, half = task & 1;
    const float* src = &lo[o * OROW + half * 16];
    float4 v0 = *(const float4*)(src + 0);
    float4 v1 = *(const float4*)(src + 4);
    float4 v2 = *(const float4*)(src + 8);
    float4 v3 = *(const float4*)(src + 12);
    float* dst = &out[(size_t)(n * COUT + o) * HW + ptile + wv * 32 + half * 16];
    *(float4*)(dst + 0) = v0;
    *(float4*)(dst + 4) = v1;
    *(float4*)(dst + 8) = v2;
    *(float4*)(dst + 12) = v3;
  }
}

extern "C" void kernel_launch(void* const* d_in, const int* in_sizes, int n_in,
                              void* d_out, int out_size, void* d_ws, size_t ws_size,
                              hipStream_t stream) {
  const float* x   = (const float*)d_in[0];  // (2, 64, 256, 512) fp32
  const float* w   = (const float*)d_in[1];  // (64, 64, 3, 3) fp32
  const float* pos = (const float*)d_in[2];  // (18, 256, 512) fp32
  float* out = (float*)d_out;                // (2, 64, 256, 512) fp32

  // ws layout: wTr bf16 [72 KB] at 0; xt bf16 [33.6 MB] at 128 KB.
  ushort* wTr = (ushort*)d_ws;
  ushort* xt = (ushort*)((char*)d_ws + (128 << 10));

  prep_w<<<(4 * NSTEP * 64 * 8 + 255) / 256, 256, 0, stream>>>(w, wTr);
  transpose_x<<<N_ * (HW / 64), 256, 0, stream>>>(x, xt);

  int nblk = N_ * (HW / PTILE);  // 2048
  sphere_conv_mfma<<<nblk, 256, 0, stream>>>(xt, wTr, pos, out);
}

// Round 4
// 271.861 us; speedup vs baseline: 1.1191x; 1.0430x over previous
//
#include <hip/hip_runtime.h>
#include <hip/hip_bf16.h>

// SphereConv N=2, CIN=64, COUT=64, H=256, W=512, K2=9.
// Round 7: attack the VMEM-issue bottleneck. Evidence: R3 (9 scattered
// VMEM/step) = 6.7k cyc/step, R6 (12/step) = 8.8k cyc/step -> time tracks
// VMEM instruction count (12/9=1.33 vs 1.30), not bytes (fixing 268MB of
// HBM fetch bought only 17us). The 8 gather loads/step are minimal; the 4
// wTr A-frag loads/step are wave- and block-uniform -> move them off the
// TCP pipe: stage wTr (72KB) into LDS once per block, ds_read_b128 in the
// loop (LDS pipe runs parallel to vector-memory). LDS region is repurposed
// for the epilogue full-line store bounce after the last MFMA (barrier).
// Keeps R6's XCD swizzle (FETCH 303->35MB) and f32 per-lane bilinear params.

constexpr int N_ = 2;
constexpr int CIN = 64;
constexpr int COUT = 64;
constexpr int H_ = 256;
constexpr int W_ = 512;
constexpr int K2 = 9;
constexpr int HW = H_ * W_;
constexpr int NSTEP = (CIN * K2) / 32;  // 18
constexpr int PTILE = 128;
constexpr int OROW = 36;  // epilogue LDS row stride (floats); 144 B
constexpr int WTR_U4 = 4 * NSTEP * 64 * 8 / 8;  // 4608 uint4 = 73728 B

typedef __attribute__((ext_vector_type(8))) short short8;
typedef __attribute__((ext_vector_type(4))) float floatx4;
typedef __attribute__((ext_vector_type(2))) float floatx2;

__device__ __forceinline__ float bfhi2f(unsigned u) {  // already-positioned bits
  return __uint_as_float(u);
}

// wTr[(ot*18 + s)*64*8 + lane*8 + j] = bf16(weight[o = 16*ot + (lane&15)]
//                                           [kk = 32s + (lane>>4)*8 + j])
__global__ void prep_w(const float* __restrict__ w, ushort* __restrict__ wTr) {
  int i = blockIdx.x * blockDim.x + threadIdx.x;
  if (i >= 4 * NSTEP * 64 * 8) return;
  int j = i & 7;
  int lane = (i >> 3) & 63;
  int s = (i >> 9) % NSTEP;
  int ot = i / (512 * NSTEP);
  int o = ot * 16 + (lane & 15);
  int kk = s * 32 + (lane >> 4) * 8 + j;
  int tap = kk >> 6, c = kk & 63;
  __hip_bfloat16 b = __float2bfloat16(w[(o * CIN + c) * K2 + tap]);
  wTr[i] = *(ushort*)&b;
}

// x[n][c][hw] fp32 -> xt[n][hw][c] bf16, via LDS tile (64 px x 64 ch).
__global__ __launch_bounds__(256) void transpose_x(
    const float* __restrict__ x, ushort* __restrict__ xt) {
  __shared__ ushort tile[64 * 72];
  int b = blockIdx.x;
  int n = b >> 11;
  int hw0 = (b & 2047) * 64;
  int tid = threadIdx.x;
  int px4 = (tid & 15) * 4;
  int cq = tid >> 4;  // 0..15
  const float* xn = x + (size_t)n * CIN * HW;
#pragma unroll
  for (int it = 0; it < 4; ++it) {
    int c = it * 16 + cq;
    float4 v = *(const float4*)&xn[(size_t)c * HW + hw0 + px4];
    __hip_bfloat16 b0 = __float2bfloat16(v.x);
    __hip_bfloat16 b1 = __float2bfloat16(v.y);
    __hip_bfloat16 b2 = __float2bfloat16(v.z);
    __hip_bfloat16 b3 = __float2bfloat16(v.w);
    tile[(px4 + 0) * 72 + c] = *(ushort*)&b0;
    tile[(px4 + 1) * 72 + c] = *(ushort*)&b1;
    tile[(px4 + 2) * 72 + c] = *(ushort*)&b2;
    tile[(px4 + 3) * 72 + c] = *(ushort*)&b3;
  }
  __syncthreads();
  ushort* xtn = xt + (size_t)n * HW * CIN;
#pragma unroll
  for (int it = 0; it < 2; ++it) {
    int task = it * 256 + tid;
    int px2 = task >> 3, chunk = task & 7;
    uint4 v = *(uint4*)&tile[px2 * 72 + chunk * 8];
    *(uint4*)&xtn[(size_t)(hw0 + px2) * 64 + chunk * 8] = v;
  }
}

__global__ __launch_bounds__(256, 2) void sphere_conv_mfma(
    const ushort* __restrict__ xt, const ushort* __restrict__ wTr,
    const float* __restrict__ pos, float* __restrict__ out) {
  // 73.7 KB: wTr copy during main loop; epilogue bounce after (repurposed).
  __shared__ __align__(16) uint4 smem[WTR_U4];
  ushort* wlds = (ushort*)smem;

  int tid = threadIdx.x;
  // XCD-chunked swizzle: consecutive tiles share an XCD's L2 (8 chunks x 256).
  int orig = blockIdx.x;
  int blk = (orig & 7) * 256 + (orig >> 3);
  int n = blk >> 10;
  int ptile = (blk & 1023) * PTILE;
  int lane = tid & 63, wv = tid >> 6;
  int col = lane & 15, quad = lane >> 4;

  // ---- stage wTr into LDS (coalesced, 18 uint4/thread) ----
  {
    const uint4* src = (const uint4*)wTr;
#pragma unroll
    for (int i = 0; i < WTR_U4 / 256; ++i) smem[i * 256 + tid] = src[i * 256 + tid];
  }

  // This wave owns 32 pixels (2 MFMA n-tiles) x all 64 COUT (4 A-tiles).
  int hw[2];
  hw[0] = ptile + wv * 32 + col;
  hw[1] = hw[0] + 16;

  const ushort* xtn = xt + (size_t)n * HW * CIN;

  floatx4 acc[2][4];
#pragma unroll
  for (int T = 0; T < 2; ++T)
#pragma unroll
    for (int ot = 0; ot < 4; ++ot) acc[T][ot] = (floatx4)0.f;

  // bilinear params, ping-pong by tap parity (all indices compile-time)
  int o00[2][2], dxo[2][2], dyo[2][2];
  float w4[2][2][4];

  auto calcParams = [&](int t) {
    int tp = t & 1;
#pragma unroll
    for (int T = 0; T < 2; ++T) {
      float py = pos[(2 * t + 0) * HW + hw[T]];
      float pxx = pos[(2 * t + 1) * HW + hw[T]];
      float y0f = floorf(py), x0f = floorf(pxx);
      float dy = py - y0f, dx = pxx - x0f;
      float y1f = y0f + 1.f, x1f = x0f + 1.f;
      float vy0 = (y0f >= 0.f && y0f <= (float)(H_ - 1)) ? 1.f : 0.f;
      float vy1 = (y1f >= 0.f && y1f <= (float)(H_ - 1)) ? 1.f : 0.f;
      float vx0 = (x0f >= 0.f && x0f <= (float)(W_ - 1)) ? 1.f : 0.f;
      float vx1 = (x1f >= 0.f && x1f <= (float)(W_ - 1)) ? 1.f : 0.f;
      w4[tp][T][0] = (1.f - dy) * (1.f - dx) * vy0 * vx0;
      w4[tp][T][1] = (1.f - dy) * dx * vy0 * vx1;
      w4[tp][T][2] = dy * (1.f - dx) * vy1 * vx0;
      w4[tp][T][3] = dy * dx * vy1 * vx1;
      int y0c = (int)fminf(fmaxf(y0f, 0.f), (float)(H_ - 1));
      int y1c = (int)fminf(fmaxf(y1f, 0.f), (float)(H_ - 1));
      int x0c = (int)fminf(fmaxf(x0f, 0.f), (float)(W_ - 1));
      int x1c = (int)fminf(fmaxf(x1f, 0.f), (float)(W_ - 1));
      o00[tp][T] = (y0c * W_ + x0c) * CIN;
      dxo[tp][T] = (x1c - x0c) * CIN;
      dyo[tp][T] = (y1c - y0c) * (W_ * CIN);
    }
  };

  // B-frag element j of lane = channel c0 + j of pixel hw[T].
  auto gather = [&](int s, short8 (&g)[2][4]) {
    int tp = (s >> 1) & 1;
    int c0 = ((s & 1) << 5) + (quad << 3);
#pragma unroll
    for (int T = 0; T < 2; ++T) {
      const ushort* p00 = xtn + (size_t)o00[tp][T] + c0;
      const ushort* p10 = p00 + dyo[tp][T];
      g[T][0] = *(const short8*)p00;
      g[T][1] = *(const short8*)(p00 + dxo[tp][T]);
      g[T][2] = *(const short8*)p10;
      g[T][3] = *(const short8*)(p10 + dxo[tp][T]);
    }
  };

  calcParams(0);
  short8 gA[2][4], gB[2][4];
  gather(0, gA);

  __syncthreads();  // staging complete before first ds_read of wlds

#pragma unroll
  for (int s = 0; s < NSTEP; ++s) {
    if (s + 1 < NSTEP) {  // prefetch next step (params first at tap boundary)
      if (((s + 1) & 1) == 0) calcParams((s + 1) >> 1);
      gather(s + 1, gB);
    }

    int tp = (s >> 1) & 1;
    short8 afr[4];
#pragma unroll
    for (int ot = 0; ot < 4; ++ot)
      afr[ot] = *(const short8*)&wlds[((ot * NSTEP + s) * 64 + lane) * 8];

    short8 bfr[2];
#pragma unroll
    for (int T = 0; T < 2; ++T) {
      const unsigned* u = (const unsigned*)&gA[T][0];
      floatx2 a2[4];
#pragma unroll
      for (int d = 0; d < 4; ++d) {
        floatx2 f = {bfhi2f(u[d] << 16), bfhi2f(u[d] & 0xFFFF0000u)};
        a2[d] = floatx2{w4[tp][T][0], w4[tp][T][0]} * f;
      }
#pragma unroll
      for (int c = 1; c < 4; ++c) {
#pragma unroll
        for (int d = 0; d < 4; ++d) {
          unsigned v = u[c * 4 + d];
          floatx2 f = {bfhi2f(v << 16), bfhi2f(v & 0xFFFF0000u)};
          a2[d] = __builtin_elementwise_fma(floatx2{w4[tp][T][c], w4[tp][T][c]}, f, a2[d]);
        }
      }
      union { unsigned q[4]; short8 s8; } pk;
#pragma unroll
      for (int d = 0; d < 4; ++d) {
        __hip_bfloat16 lo = __float2bfloat16(a2[d].x);
        __hip_bfloat16 hi = __float2bfloat16(a2[d].y);
        pk.q[d] = ((unsigned)*(ushort*)&hi << 16) | *(ushort*)&lo;
      }
      bfr[T] = pk.s8;
    }

#pragma unroll
    for (int T = 0; T < 2; ++T)
#pragma unroll
      for (int ot = 0; ot < 4; ++ot)
        acc[T][ot] = __builtin_amdgcn_mfma_f32_16x16x32_bf16(afr[ot], bfr[T], acc[T][ot], 0, 0, 0);

    if (s + 1 < NSTEP) {  // SSA rename under full unroll, no real movs
#pragma unroll
      for (int T = 0; T < 2; ++T)
#pragma unroll
        for (int q = 0; q < 4; ++q) gA[T][q] = gB[T][q];
    }
  }

  // ---- epilogue: repurpose LDS as per-wave bounce -> full-line stores ----
  __syncthreads();  // all waves done reading wlds before overwrite
  float* lo = (float*)smem + wv * (64 * OROW);
#pragma unroll
  for (int T = 0; T < 2; ++T)
#pragma unroll
    for (int ot = 0; ot < 4; ++ot)
#pragma unroll
      for (int r = 0; r < 4; ++r)
        lo[(ot * 16 + quad * 4 + r) * OROW + T * 16 + col] = acc[T][ot][r];
  // same-wave write->read: no barrier needed
#pragma unroll
  for (int it = 0; it < 2; ++it) {
    int task = it * 64 + lane;
    int o = task >> 1, half = task & 1;
    const float* src = &lo[o * OROW + half * 16];
    float4 v0 = *(const float4*)(src + 0);
    float4 v1 = *(const float4*)(src + 4);
    float4 v2 = *(const float4*)(src + 8);
    float4 v3 = *(const float4*)(src + 12);
    float* dst = &out[(size_t)(n * COUT + o) * HW + ptile + wv * 32 + half * 16];
    *(float4*)(dst + 0) = v0;
    *(float4*)(dst + 4) = v1;
    *(float4*)(dst + 8) = v2;
    *(float4*)(dst + 12) = v3;
  }
}

extern "C" void kernel_launch(void* const* d_in, const int* in_sizes, int n_in,
                              void* d_out, int out_size, void* d_ws, size_t ws_size,
                              hipStream_t stream) {
  const float* x   = (const float*)d_in[0];  // (2, 64, 256, 512) fp32
  const float* w   = (const float*)d_in[1];  // (64, 64, 3, 3) fp32
  const float* pos = (const float*)d_in[2];  // (18, 256, 512) fp32
  float* out = (float*)d_out;                // (2, 64, 256, 512) fp32

  // ws layout: wTr bf16 [72 KB] at 0; xt bf16 [33.6 MB] at 128 KB.
  ushort* wTr = (ushort*)d_ws;
  ushort* xt = (ushort*)((char*)d_ws + (128 << 10));

  prep_w<<<(4 * NSTEP * 64 * 8 + 255) / 256, 256, 0, stream>>>(w, wTr);
  transpose_x<<<N_ * (HW / 64), 256, 0, stream>>>(x, xt);

  int nblk = N_ * (HW / PTILE);  // 2048
  sphere_conv_mfma<<<nblk, 256, 0, stream>>>(xt, wTr, pos, out);
}